// Round 28
// baseline (192.067 us; speedup 1.0000x reference)
//
#include <hip/hip_runtime.h>
#include <hip/hip_bf16.h>
#include <stdint.h>

#define MB_ 8192
#define FD  512
#define OD  512
#define KD  8704
#define KBASIS 8192
#define BT_KS   1088
#define BT_CHUNKS_PER_CT (BT_KS * 128)
#define BT_BYTES_PER_CT  (BT_CHUNKS_PER_CT * 16)
#define TOFF4 65536      // t-panel offset in fallback 4-buf body
#define WS_T    16777216ull
#define WS_XBF  8388608ull
#define WS_BT2  8912896ull
#define WS_P0_OFF (WS_T + WS_XBF + WS_BT2)
#define WS_P1_OFF (WS_P0_OFF + 8388608ull)
#define WS_P2_OFF (WS_P1_OFF + 8388608ull)
#define WS_P3_OFF (WS_P2_OFF + 8388608ull)
#define WS_NEED4  (WS_P3_OFF + 8388608ull)   // 67,633,152

typedef __attribute__((ext_vector_type(4))) float f32x4;
typedef __attribute__((ext_vector_type(8))) short bf16x8;
typedef __attribute__((ext_vector_type(4))) unsigned int u32x4;
typedef __attribute__((ext_vector_type(2))) unsigned int u32x2;

__device__ __forceinline__ void gload_lds16(const void* g, void* l) {
  __builtin_amdgcn_global_load_lds((const __attribute__((address_space(1))) void*)g,
                                   (__attribute__((address_space(3))) void*)l,
                                   16, 0, 0);
}

__device__ __forceinline__ uint32_t bf_rtn(float f) {
  uint32_t u = __float_as_uint(f);
  return (u + 0x7fffu + ((u >> 16) & 1u)) >> 16;
}

__device__ __forceinline__ uint32_t pk(float a, float b) {
  uint32_t r;
  asm("v_cvt_pk_bf16_f32 %0, %1, %2" : "=v"(r) : "v"(a), "v"(b));
  return r;
}

// ---------------- phase 1 (fused): tanh/xbf + bt2 repack (PROVEN r27) -------
__global__ __launch_bounds__(256) void k_prep(const float* __restrict__ x,
                                              float* __restrict__ t,
                                              uint16_t* __restrict__ xbf,
                                              const float* __restrict__ coeffs,
                                              const float* __restrict__ bw,
                                              uint16_t* __restrict__ bt2,
                                              float* __restrict__ out) {
  if (blockIdx.x < 4096) {
    int i = blockIdx.x * 256 + threadIdx.x;
    f32x4 v = ((const f32x4*)x)[i];
    f32x4 tv;
    tv[0] = tanhf(v[0]); tv[1] = tanhf(v[1]);
    tv[2] = tanhf(v[2]); tv[3] = tanhf(v[3]);
    ((f32x4*)t)[i] = tv;
    u32x2 p;
    p[0] = pk(v[0], v[1]);
    p[1] = pk(v[2], v[3]);
    ((u32x2*)xbf)[i] = p;
  } else {
    int tid = (blockIdx.x - 4096) * 256 + threadIdx.x;
    {
      int o = tid & 511, i = tid >> 9;
      const f32x4* src = (const f32x4*)(coeffs + (((size_t)(i * 512 + o)) << 4));
      f32x4 c0 = src[0], c1 = src[1], c2 = src[2], c3 = src[3];
      u32x4 qa, qb;
      qa[0] = pk(c0[0], c0[1]);
      qa[1] = pk(c0[2], c0[3]);
      qa[2] = pk(c1[0], c1[1]);
      qa[3] = pk(c1[2], c1[3]);
      qb[0] = pk(c2[0], c2[1]);
      qb[1] = pk(c2[2], c2[3]);
      qb[2] = pk(c3[0], c3[1]);
      qb[3] = pk(c3[2], c3[3]);
      int slo = ((i >> 2) << 3) | (i & 3);
      size_t cidx = (size_t)(o >> 7) * BT_CHUNKS_PER_CT + (size_t)slo * 128 + (o & 127);
      u32x4* base = (u32x4*)bt2;
      base[cidx]       = qa;
      base[cidx + 512] = qb;
    }
    {
      int o2 = tid >> 9, i2 = tid & 511;
      size_t cidx = (size_t)(o2 >> 7) * BT_CHUNKS_PER_CT + (size_t)(1024 + (i2 >> 3)) * 128 + (o2 & 127);
      bt2[cidx * 8 + (i2 & 7)] = (uint16_t)bf_rtn(bw[i2 * 512 + o2]);
    }
    if (tid == 0) out[(size_t)MB_ * OD] = 0.0f;
  }
}

// ============ NEW: K-quarter body, 2-buf per-step counted pipeline ==========
// Q in 0..3; steps S0..S0+33 (Q3: basis local 0..25, residual 26..33).
// LDS/block: B 2x16KB @0, t 2x2KB @32768 (36KB -> 4 blocks/CU at (512,8)).
// Per fast step: chains -> MFMA (LDS reads retired) -> s_barrier (reads done)
// -> stage s+2 into just-read buf -> vmcnt(3|2) counted fence (r24 invariant).
template <int Q>
__device__ __forceinline__ void gemm_q(int bx, char* lds,
                                       const float* __restrict__ t,
                                       const uint16_t* __restrict__ xbf,
                                       const uint16_t* __restrict__ bt2,
                                       uint16_t* __restrict__ p) {
  constexpr int S0 = 34 * Q;
  constexpr int NFAST = (Q == 3) ? 22 : 32;

  const int tid  = threadIdx.x;
  const int lane = tid & 63;
  const int wid  = tid >> 6;
  const int wr   = wid >> 1;          // 0..3 (row group of 32)
  const int wc   = wid & 1;           // 0..1 (col group of 64)
  const int l15  = lane & 15, l4 = lane >> 4;

  int idx = bx >> 3;
  int rt  = (bx & 7) * 8 + (idx >> 2);
  int ct  = idx & 3;
  const int brow = rt << 7, bcol = ct << 7;

  const char* btbase = (const char*)bt2 + (size_t)ct * BT_BYTES_PER_CT;

  const char* bb0 = lds + l4 * 2048 + (wc * 64 + l15) * 16;
  const char* tb0 = lds + 32768 + (wr * 32 + l15) * 16 + l4 * 4;
  char* sBl = lds + tid * 16;
  char* sTl = lds + 32768 + wid * 1024 + lane * 16;

  const char* sBgBase = btbase + (size_t)tid * 16;
  const char* sTgBase = (const char*)t + (((size_t)(brow + wid * 64 + lane)) * FD) * 4;

  f32x4 acc[2][4];
#pragma unroll
  for (int m = 0; m < 2; ++m)
#pragma unroll
    for (int n = 0; n < 4; ++n) acc[m][n] = (f32x4)0.0f;

  auto stageB = [&](int gs, int b2) {
    const char* src = sBgBase + ((size_t)gs << 14);
    gload_lds16(src, sBl + b2 * 16384);
    gload_lds16(src + 8192, sBl + b2 * 16384 + 8192);
  };
  auto stageT = [&](int gs, int b2) {
    if (wid < 2)
      gload_lds16(sTgBase + ((size_t)gs << 4), sTl + b2 * 2048);
  };
  auto chains = [&](const char* tb, u32x4& af00, u32x4& af01,
                    u32x4& af10, u32x4& af11) {
#pragma unroll
    for (int m = 0; m < 2; ++m) {
      float tv = *(const float*)(tb + m * 256);
      float c2 = tv + tv;
      float T0 = 1.0f, T1 = tv;
      float T2  = __builtin_fmaf(c2, T1,  -T0);
      float T3  = __builtin_fmaf(c2, T2,  -T1);
      float T4  = __builtin_fmaf(c2, T3,  -T2);
      float T5  = __builtin_fmaf(c2, T4,  -T3);
      float T6  = __builtin_fmaf(c2, T5,  -T4);
      float T7  = __builtin_fmaf(c2, T6,  -T5);
      float T8  = __builtin_fmaf(c2, T7,  -T6);
      float T9  = __builtin_fmaf(c2, T8,  -T7);
      float T10 = __builtin_fmaf(c2, T9,  -T8);
      float T11 = __builtin_fmaf(c2, T10, -T9);
      float T12 = __builtin_fmaf(c2, T11, -T10);
      float T13 = __builtin_fmaf(c2, T12, -T11);
      float T14 = __builtin_fmaf(c2, T13, -T12);
      float T15 = __builtin_fmaf(c2, T14, -T13);
      u32x4 lo, hi;
      lo[0] = pk(T0,  T1);  lo[1] = pk(T2,  T3);
      lo[2] = pk(T4,  T5);  lo[3] = pk(T6,  T7);
      hi[0] = pk(T8,  T9);  hi[1] = pk(T10, T11);
      hi[2] = pk(T12, T13); hi[3] = pk(T14, T15);
      if (m == 0) { af00 = lo; af01 = hi; }
      else        { af10 = lo; af11 = hi; }
    }
  };
  auto mfma16 = [&](const char* bb, const u32x4& af00, const u32x4& af01,
                    const u32x4& af10, const u32x4& af11) {
    bf16x8 a00 = *(const bf16x8*)&af00;
    bf16x8 a01 = *(const bf16x8*)&af01;
    bf16x8 a10 = *(const bf16x8*)&af10;
    bf16x8 a11 = *(const bf16x8*)&af11;
#pragma unroll
    for (int n = 0; n < 4; ++n) {
      bf16x8 b0 = *(const bf16x8*)(bb + n * 256);
      bf16x8 b1 = *(const bf16x8*)(bb + 8192 + n * 256);
      acc[0][n] = __builtin_amdgcn_mfma_f32_16x16x32_bf16(a00, b0, acc[0][n], 0, 0, 0);
      acc[1][n] = __builtin_amdgcn_mfma_f32_16x16x32_bf16(a10, b0, acc[1][n], 0, 0, 0);
      acc[0][n] = __builtin_amdgcn_mfma_f32_16x16x32_bf16(a01, b1, acc[0][n], 0, 0, 0);
      acc[1][n] = __builtin_amdgcn_mfma_f32_16x16x32_bf16(a11, b1, acc[1][n], 0, 0, 0);
    }
  };
  auto fence = [&]() {   // counted: only the just-issued batch rides
    if (wid < 2) asm volatile("s_waitcnt vmcnt(3)" ::: "memory");
    else         asm volatile("s_waitcnt vmcnt(2)" ::: "memory");
    __builtin_amdgcn_s_barrier();
    __builtin_amdgcn_sched_barrier(0);
  };

  // prologue: stage steps 0,1 into bufs 0,1; drain batch0, leave batch1
  stageB(S0 + 0, 0); stageT(S0 + 0, 0);
  stageB(S0 + 1, 1); stageT(S0 + 1, 1);
  fence();

  auto fastbody = [&](int s, int cur) {   // cur = s&1, compile-time
    u32x4 af00, af01, af10, af11;
    chains(tb0 + cur * 2048, af00, af01, af10, af11);
    __builtin_amdgcn_s_setprio(1);
    mfma16(bb0 + cur * 16384, af00, af01, af10, af11);
    __builtin_amdgcn_s_setprio(0);
    __builtin_amdgcn_s_barrier();          // all waves done reading buf cur
    __builtin_amdgcn_sched_barrier(0);
    stageB(S0 + s + 2, cur);
    stageT(S0 + s + 2, cur);
    fence();
  };

  for (int s = 0; s < NFAST; s += 2) {
    fastbody(s, 0);
    fastbody(s + 1, 1);
  }

  if constexpr (Q < 3) {
    // tail steps 32,33: pre-staged; one full drain between
#pragma unroll
    for (int s = 32; s < 34; ++s) {
      u32x4 af00, af01, af10, af11;
      chains(tb0 + (s & 1) * 2048, af00, af01, af10, af11);
      mfma16(bb0 + (s & 1) * 16384, af00, af01, af10, af11);
      __syncthreads();
    }
  } else {
    const int row = brow + wr * 32 + l15;
    const uint16_t* x0 = xbf + (size_t)row * FD;
    const uint16_t* x1 = x0 + (size_t)16 * FD;
    // tail local steps 22..33 (basis 22..25, residual 26..33), full drains.
    for (int s = 22; s < 34; ++s) {
      u32x4 af00, af01, af10, af11;
      if (s < 26) {
        chains(tb0 + (s & 1) * 2048, af00, af01, af10, af11);
      } else {                             // residual: direct register loads
        int kres = ((s - 26) << 6) + l4 * 8;
        af00 = *(const u32x4*)(x0 + kres);
        af01 = *(const u32x4*)(x0 + kres + 32);
        af10 = *(const u32x4*)(x1 + kres);
        af11 = *(const u32x4*)(x1 + kres + 32);
      }
      mfma16(bb0 + (s & 1) * 16384, af00, af01, af10, af11);
      __syncthreads();                     // reads done + all gloads drained
      if (s + 2 <= 33) {                   // stage into the just-read buf
        stageB(S0 + s + 2, (s + 2) & 1);
        if (s + 2 <= 25) stageT(S0 + s + 2, (s + 2) & 1);
      }
    }
    __syncthreads();                       // final staging ordering (harmless)
  }

  // epilogue: bf16 partial store (C/D layout m89)
#pragma unroll
  for (int m = 0; m < 2; ++m)
#pragma unroll
    for (int n = 0; n < 4; ++n)
#pragma unroll
      for (int r = 0; r < 4; ++r) {
        int grow = brow + wr * 32 + m * 16 + l4 * 4 + r;
        int gcol = bcol + wc * 64 + n * 16 + l15;
        p[(size_t)grow * OD + gcol] = (uint16_t)bf_rtn(acc[m][n][r]);
      }
}

__global__ __launch_bounds__(512, 8) void k_gemm_q(const float* __restrict__ t,
                                                   const uint16_t* __restrict__ xbf,
                                                   const uint16_t* __restrict__ bt2,
                                                   uint16_t* __restrict__ p0,
                                                   uint16_t* __restrict__ p1,
                                                   uint16_t* __restrict__ p2,
                                                   uint16_t* __restrict__ p3) {
  __shared__ __align__(128) char lds[36864];  // B 2x16KB | t 2x2KB
  int q = blockIdx.x >> 8, bx = blockIdx.x & 255;
  if (q == 0)      gemm_q<0>(bx, lds, t, xbf, bt2, p0);
  else if (q == 1) gemm_q<1>(bx, lds, t, xbf, bt2, p1);
  else if (q == 2) gemm_q<2>(bx, lds, t, xbf, bt2, p2);
  else             gemm_q<3>(bx, lds, t, xbf, bt2, p3);
}

__global__ __launch_bounds__(256) void k_add4(float* __restrict__ out,
                                              const uint16_t* __restrict__ p0,
                                              const uint16_t* __restrict__ p1,
                                              const uint16_t* __restrict__ p2,
                                              const uint16_t* __restrict__ p3) {
  size_t i = ((size_t)blockIdx.x * 256 + threadIdx.x) * 4;
  u32x2 a0 = *(const u32x2*)(p0 + i);
  u32x2 a1 = *(const u32x2*)(p1 + i);
  u32x2 a2 = *(const u32x2*)(p2 + i);
  u32x2 a3 = *(const u32x2*)(p3 + i);
  f32x4 o;
  o[0] = (__uint_as_float(a0[0] << 16)         + __uint_as_float(a1[0] << 16)) +
         (__uint_as_float(a2[0] << 16)         + __uint_as_float(a3[0] << 16));
  o[1] = (__uint_as_float(a0[0] & 0xffff0000u) + __uint_as_float(a1[0] & 0xffff0000u)) +
         (__uint_as_float(a2[0] & 0xffff0000u) + __uint_as_float(a3[0] & 0xffff0000u));
  o[2] = (__uint_as_float(a0[1] << 16)         + __uint_as_float(a1[1] << 16)) +
         (__uint_as_float(a2[1] << 16)         + __uint_as_float(a3[1] << 16));
  o[3] = (__uint_as_float(a0[1] & 0xffff0000u) + __uint_as_float(a1[1] & 0xffff0000u)) +
         (__uint_as_float(a2[1] & 0xffff0000u) + __uint_as_float(a3[1] & 0xffff0000u));
  *(f32x4*)(out + i) = o;
}

// ============ FALLBACK (r27 verbatim): K-halves, 4-buf paired pipeline ======
template <int MODE>
__device__ __forceinline__ void gemm_h(int bx, char* lds,
                                       const float* __restrict__ t,
                                       const uint16_t* __restrict__ xbf,
                                       const uint16_t* __restrict__ bt2,
                                       uint16_t* __restrict__ p) {
  constexpr int S0 = (MODE == 2) ? 68 : 0;

  const int tid  = threadIdx.x;
  const int lane = tid & 63;
  const int wid  = tid >> 6;
  const int wr   = wid >> 1;
  const int wc   = wid & 1;
  const int l15  = lane & 15, l4 = lane >> 4;

  int idx = bx >> 3;
  int rt  = (bx & 7) * 8 + (idx >> 2);
  int ct  = idx & 3;
  const int brow = rt << 7, bcol = ct << 7;

  const char* btbase = (const char*)bt2 + (size_t)ct * BT_BYTES_PER_CT;
  const int row = brow + wr * 32 + l15;
  const uint16_t* x0 = xbf + (size_t)row * FD;
  const uint16_t* x1 = x0 + (size_t)16 * FD;

  const char* bb0 = lds + l4 * 2048 + (wc * 64 + l15) * 16;
  const char* tb0 = lds + TOFF4 + (wr * 32 + l15) * 16 + l4 * 4;
  char* sBl = lds + tid * 16;
  char* sTl = lds + TOFF4 + wid * 1024 + lane * 16;

  const char* sBgBase = btbase + (size_t)tid * 16;
  const char* sTgBase = (const char*)t + (((size_t)(brow + wid * 64 + lane)) * FD) * 4;

  f32x4 acc[2][4];
#pragma unroll
  for (int m = 0; m < 2; ++m)
#pragma unroll
    for (int n = 0; n < 4; ++n) acc[m][n] = (f32x4)0.0f;

  u32x4 pf00 = {}, pf01 = {}, pf10 = {}, pf11 = {};

  auto stageB = [&](int gs, int b2) {
    const char* src = sBgBase + ((size_t)gs << 14);
    gload_lds16(src, sBl + b2 * 16384);
    gload_lds16(src + 8192, sBl + b2 * 16384 + 8192);
  };
  auto stageT = [&](int gs, int b2) {
    if (wid < 2)
      gload_lds16(sTgBase + ((size_t)gs << 4), sTl + b2 * 2048);
  };
  auto chains = [&](const char* tb, u32x4& af00, u32x4& af01,
                    u32x4& af10, u32x4& af11) {
#pragma unroll
    for (int m = 0; m < 2; ++m) {
      float tv = *(const float*)(tb + m * 256);
      float c2 = tv + tv;
      float T0 = 1.0f, T1 = tv;
      float T2  = __builtin_fmaf(c2, T1,  -T0);
      float T3  = __builtin_fmaf(c2, T2,  -T1);
      float T4  = __builtin_fmaf(c2, T3,  -T2);
      float T5  = __builtin_fmaf(c2, T4,  -T3);
      float T6  = __builtin_fmaf(c2, T5,  -T4);
      float T7  = __builtin_fmaf(c2, T6,  -T5);
      float T8  = __builtin_fmaf(c2, T7,  -T6);
      float T9  = __builtin_fmaf(c2, T8,  -T7);
      float T10 = __builtin_fmaf(c2, T9,  -T8);
      float T11 = __builtin_fmaf(c2, T10, -T9);
      float T12 = __builtin_fmaf(c2, T11, -T10);
      float T13 = __builtin_fmaf(c2, T12, -T11);
      float T14 = __builtin_fmaf(c2, T13, -T12);
      float T15 = __builtin_fmaf(c2, T14, -T13);
      u32x4 lo, hi;
      lo[0] = pk(T0,  T1);  lo[1] = pk(T2,  T3);
      lo[2] = pk(T4,  T5);  lo[3] = pk(T6,  T7);
      hi[0] = pk(T8,  T9);  hi[1] = pk(T10, T11);
      hi[2] = pk(T12, T13); hi[3] = pk(T14, T15);
      if (m == 0) { af00 = lo; af01 = hi; }
      else        { af10 = lo; af11 = hi; }
    }
  };
  auto mfma16 = [&](const char* bb, const u32x4& af00, const u32x4& af01,
                    const u32x4& af10, const u32x4& af11) {
    bf16x8 a00 = *(const bf16x8*)&af00;
    bf16x8 a01 = *(const bf16x8*)&af01;
    bf16x8 a10 = *(const bf16x8*)&af10;
    bf16x8 a11 = *(const bf16x8*)&af11;
#pragma unroll
    for (int n = 0; n < 4; ++n) {
      bf16x8 b0 = *(const bf16x8*)(bb + n * 256);
      bf16x8 b1 = *(const bf16x8*)(bb + 8192 + n * 256);
      acc[0][n] = __builtin_amdgcn_mfma_f32_16x16x32_bf16(a00, b0, acc[0][n], 0, 0, 0);
      acc[1][n] = __builtin_amdgcn_mfma_f32_16x16x32_bf16(a10, b0, acc[1][n], 0, 0, 0);
      acc[0][n] = __builtin_amdgcn_mfma_f32_16x16x32_bf16(a01, b1, acc[0][n], 0, 0, 0);
      acc[1][n] = __builtin_amdgcn_mfma_f32_16x16x32_bf16(a11, b1, acc[1][n], 0, 0, 0);
    }
  };
  auto fence_bar = [&]() {
    if (wid < 2) asm volatile("s_waitcnt vmcnt(6)" ::: "memory");
    else         asm volatile("s_waitcnt vmcnt(4)" ::: "memory");
    __builtin_amdgcn_s_barrier();
    __builtin_amdgcn_sched_barrier(0);
  };
  auto pairbody = [&](int s, int c0, int c1) {
    u32x4 af00, af01, af10, af11;
    chains(tb0 + c0 * 2048, af00, af01, af10, af11);
    __builtin_amdgcn_s_setprio(1);
    mfma16(bb0 + c0 * 16384, af00, af01, af10, af11);
    __builtin_amdgcn_s_setprio(0);
    chains(tb0 + c1 * 2048, af00, af01, af10, af11);
    __builtin_amdgcn_s_setprio(1);
    mfma16(bb0 + c1 * 16384, af00, af01, af10, af11);
    __builtin_amdgcn_s_setprio(0);
    __builtin_amdgcn_s_barrier();
    __builtin_amdgcn_sched_barrier(0);
    stageB(S0 + s + 4, c0); stageT(S0 + s + 4, c0);
    stageB(S0 + s + 5, c1); stageT(S0 + s + 5, c1);
    fence_bar();
  };

  stageB(S0 + 0, 0); stageT(S0 + 0, 0);
  stageB(S0 + 1, 1); stageT(S0 + 1, 1);
  stageB(S0 + 2, 2); stageT(S0 + 2, 2);
  stageB(S0 + 3, 3); stageT(S0 + 3, 3);
  fence_bar();

  if constexpr (MODE == 1) {
    for (int s = 0; s < 64; s += 4) { pairbody(s, 0, 1); pairbody(s + 2, 2, 3); }
    for (int s = 64; s < 68; ++s) {
      u32x4 af00, af01, af10, af11;
      chains(tb0 + (s & 3) * 2048, af00, af01, af10, af11);
      mfma16(bb0 + (s & 3) * 16384, af00, af01, af10, af11);
      __syncthreads();
    }
  } else {
    for (int s = 0; s < 56; s += 4) { pairbody(s, 0, 1); pairbody(s + 2, 2, 3); }
    for (int s = 56; s < 68; ++s) {
      u32x4 af00 = pf00, af01 = pf01, af10 = pf10, af11 = pf11;
      if (s >= 58 && s <= 65) stageB(68 + s + 2, (s + 2) & 3);
      if (s >= 59 && s <= 66) {
        int kres = ((s + 1 - 60) << 6) + l4 * 8;
        pf00 = *(const u32x4*)(x0 + kres);
        pf01 = *(const u32x4*)(x0 + kres + 32);
        pf10 = *(const u32x4*)(x1 + kres);
        pf11 = *(const u32x4*)(x1 + kres + 32);
      }
      if (s < 60) chains(tb0 + (s & 3) * 2048, af00, af01, af10, af11);
      mfma16(bb0 + (s & 3) * 16384, af00, af01, af10, af11);
      __syncthreads();
    }
  }

#pragma unroll
  for (int m = 0; m < 2; ++m)
#pragma unroll
    for (int n = 0; n < 4; ++n)
#pragma unroll
      for (int r = 0; r < 4; ++r) {
        int grow = brow + wr * 32 + m * 16 + l4 * 4 + r;
        int gcol = bcol + wc * 64 + n * 16 + l15;
        p[(size_t)grow * OD + gcol] = (uint16_t)bf_rtn(acc[m][n][r]);
      }
}

__global__ __launch_bounds__(512, 4) void k_gemm_split(const float* __restrict__ t,
                                                       const uint16_t* __restrict__ xbf,
                                                       const uint16_t* __restrict__ bt2,
                                                       uint16_t* __restrict__ p0b,
                                                       uint16_t* __restrict__ p1b) {
  __shared__ __align__(128) char lds[73728];
  if (blockIdx.x < 256) gemm_h<1>(blockIdx.x,       lds, t, xbf, bt2, p0b);
  else                  gemm_h<2>(blockIdx.x - 256, lds, t, xbf, bt2, p1b);
}

__global__ __launch_bounds__(256) void k_add2(float* __restrict__ out,
                                              const uint16_t* __restrict__ p0b,
                                              const uint16_t* __restrict__ p1b) {
  size_t i = ((size_t)blockIdx.x * 256 + threadIdx.x) * 4;
  u32x2 q = *(const u32x2*)(p0b + i);
  u32x2 p = *(const u32x2*)(p1b + i);
  f32x4 a;
  a[0] = __uint_as_float(q[0] << 16)         + __uint_as_float(p[0] << 16);
  a[1] = __uint_as_float(q[0] & 0xffff0000u) + __uint_as_float(p[0] & 0xffff0000u);
  a[2] = __uint_as_float(q[1] << 16)         + __uint_as_float(p[1] << 16);
  a[3] = __uint_as_float(q[1] & 0xffff0000u) + __uint_as_float(p[1] & 0xffff0000u);
  *(f32x4*)(out + i) = a;
}

extern "C" void kernel_launch(void* const* d_in, const int* in_sizes, int n_in,
                              void* d_out, int out_size, void* d_ws, size_t ws_size,
                              hipStream_t stream) {
  const float* x      = (const float*)d_in[0];
  const float* coeffs = (const float*)d_in[1];
  const float* bw     = (const float*)d_in[2];
  float* out = (float*)d_out;
  char* ws = (char*)d_ws;

  float*    t   = (float*)ws;
  uint16_t* xbf = (uint16_t*)(ws + WS_T);
  uint16_t* bt2 = (uint16_t*)(ws + WS_T + WS_XBF);
  uint16_t* p0  = (uint16_t*)(ws + WS_P0_OFF);
  uint16_t* p1  = (uint16_t*)(ws + WS_P1_OFF);
  uint16_t* p2  = (uint16_t*)(ws + WS_P2_OFF);
  uint16_t* p3  = (uint16_t*)(ws + WS_P3_OFF);

  k_prep<<<5120, 256, 0, stream>>>(x, t, xbf, coeffs, bw, bt2, out);
  if (ws_size >= WS_NEED4) {
    k_gemm_q<<<1024, 512, 0, stream>>>(t, xbf, bt2, p0, p1, p2, p3);
    k_add4<<<4096, 256, 0, stream>>>(out, p0, p1, p2, p3);
  } else {
    k_gemm_split<<<512, 512, 0, stream>>>(t, xbf, bt2, p0, p1);
    k_add2<<<4096, 256, 0, stream>>>(out, p0, p1);
  }
}

// Round 29
// 107.171 us; speedup vs baseline: 1.7922x; 1.7922x over previous
//
#include <hip/hip_runtime.h>
#include <hip/hip_bf16.h>
#include <stdint.h>

#define MB_ 8192
#define FD  512
#define OD  512
#define KD  8704
#define KBASIS 8192
#define BT_KS   1088
#define BT_CHUNKS_PER_CT (BT_KS * 128)
#define BT_BYTES_PER_CT  (BT_CHUNKS_PER_CT * 16)
#define TOFF4 65536      // t-panel offset in fallback 4-buf body
#define WS_T    16777216ull
#define WS_XBF  8388608ull
#define WS_BT2  8912896ull
#define WS_P0_OFF (WS_T + WS_XBF + WS_BT2)
#define WS_P1_OFF (WS_P0_OFF + 8388608ull)
#define WS_P2_OFF (WS_P1_OFF + 8388608ull)
#define WS_P3_OFF (WS_P2_OFF + 8388608ull)
#define WS_NEED4  (WS_P3_OFF + 8388608ull)   // 67,633,152

typedef __attribute__((ext_vector_type(4))) float f32x4;
typedef __attribute__((ext_vector_type(8))) short bf16x8;
typedef __attribute__((ext_vector_type(4))) unsigned int u32x4;
typedef __attribute__((ext_vector_type(2))) unsigned int u32x2;

__device__ __forceinline__ void gload_lds16(const void* g, void* l) {
  __builtin_amdgcn_global_load_lds((const __attribute__((address_space(1))) void*)g,
                                   (__attribute__((address_space(3))) void*)l,
                                   16, 0, 0);
}

__device__ __forceinline__ uint32_t bf_rtn(float f) {
  uint32_t u = __float_as_uint(f);
  return (u + 0x7fffu + ((u >> 16) & 1u)) >> 16;
}

__device__ __forceinline__ uint32_t pk(float a, float b) {
  uint32_t r;
  asm("v_cvt_pk_bf16_f32 %0, %1, %2" : "=v"(r) : "v"(a), "v"(b));
  return r;
}

// ---------------- phase 1 (fused): tanh/xbf + bt2 repack (PROVEN r27) -------
__global__ __launch_bounds__(256) void k_prep(const float* __restrict__ x,
                                              float* __restrict__ t,
                                              uint16_t* __restrict__ xbf,
                                              const float* __restrict__ coeffs,
                                              const float* __restrict__ bw,
                                              uint16_t* __restrict__ bt2,
                                              float* __restrict__ out) {
  if (blockIdx.x < 4096) {
    int i = blockIdx.x * 256 + threadIdx.x;
    f32x4 v = ((const f32x4*)x)[i];
    f32x4 tv;
    tv[0] = tanhf(v[0]); tv[1] = tanhf(v[1]);
    tv[2] = tanhf(v[2]); tv[3] = tanhf(v[3]);
    ((f32x4*)t)[i] = tv;
    u32x2 p;
    p[0] = pk(v[0], v[1]);
    p[1] = pk(v[2], v[3]);
    ((u32x2*)xbf)[i] = p;
  } else {
    int tid = (blockIdx.x - 4096) * 256 + threadIdx.x;
    {
      int o = tid & 511, i = tid >> 9;
      const f32x4* src = (const f32x4*)(coeffs + (((size_t)(i * 512 + o)) << 4));
      f32x4 c0 = src[0], c1 = src[1], c2 = src[2], c3 = src[3];
      u32x4 qa, qb;
      qa[0] = pk(c0[0], c0[1]);
      qa[1] = pk(c0[2], c0[3]);
      qa[2] = pk(c1[0], c1[1]);
      qa[3] = pk(c1[2], c1[3]);
      qb[0] = pk(c2[0], c2[1]);
      qb[1] = pk(c2[2], c2[3]);
      qb[2] = pk(c3[0], c3[1]);
      qb[3] = pk(c3[2], c3[3]);
      int slo = ((i >> 2) << 3) | (i & 3);
      size_t cidx = (size_t)(o >> 7) * BT_CHUNKS_PER_CT + (size_t)slo * 128 + (o & 127);
      u32x4* base = (u32x4*)bt2;
      base[cidx]       = qa;
      base[cidx + 512] = qb;
    }
    {
      int o2 = tid >> 9, i2 = tid & 511;
      size_t cidx = (size_t)(o2 >> 7) * BT_CHUNKS_PER_CT + (size_t)(1024 + (i2 >> 3)) * 128 + (o2 & 127);
      bt2[cidx * 8 + (i2 & 7)] = (uint16_t)bf_rtn(bw[i2 * 512 + o2]);
    }
    if (tid == 0) out[(size_t)MB_ * OD] = 0.0f;
  }
}

// ============ K-quarter body, 2-buf per-step counted pipeline (r28-PROVEN) ==
// Q in 0..3; steps S0..S0+33 (Q3: basis local 0..25, residual 26..33).
// LDS/block: B 2x16KB @0, t 2x2KB @32768. ROUND-29: launch_bounds (512,6)
// -> VGPR cap ~84 (body needs 64, no spills; r28's (512,8) cap 64 spilled
// acc to scratch: 508MB WRITE). 3 blocks/CU = 24 waves/CU.
template <int Q>
__device__ __forceinline__ void gemm_q(int bx, char* lds,
                                       const float* __restrict__ t,
                                       const uint16_t* __restrict__ xbf,
                                       const uint16_t* __restrict__ bt2,
                                       uint16_t* __restrict__ p) {
  constexpr int S0 = 34 * Q;
  constexpr int NFAST = (Q == 3) ? 22 : 32;

  const int tid  = threadIdx.x;
  const int lane = tid & 63;
  const int wid  = tid >> 6;
  const int wr   = wid >> 1;          // 0..3 (row group of 32)
  const int wc   = wid & 1;           // 0..1 (col group of 64)
  const int l15  = lane & 15, l4 = lane >> 4;

  int idx = bx >> 3;
  int rt  = (bx & 7) * 8 + (idx >> 2);
  int ct  = idx & 3;
  const int brow = rt << 7, bcol = ct << 7;

  const char* btbase = (const char*)bt2 + (size_t)ct * BT_BYTES_PER_CT;

  const char* bb0 = lds + l4 * 2048 + (wc * 64 + l15) * 16;
  const char* tb0 = lds + 32768 + (wr * 32 + l15) * 16 + l4 * 4;
  char* sBl = lds + tid * 16;
  char* sTl = lds + 32768 + wid * 1024 + lane * 16;

  const char* sBgBase = btbase + (size_t)tid * 16;
  const char* sTgBase = (const char*)t + (((size_t)(brow + wid * 64 + lane)) * FD) * 4;

  f32x4 acc[2][4];
#pragma unroll
  for (int m = 0; m < 2; ++m)
#pragma unroll
    for (int n = 0; n < 4; ++n) acc[m][n] = (f32x4)0.0f;

  auto stageB = [&](int gs, int b2) {
    const char* src = sBgBase + ((size_t)gs << 14);
    gload_lds16(src, sBl + b2 * 16384);
    gload_lds16(src + 8192, sBl + b2 * 16384 + 8192);
  };
  auto stageT = [&](int gs, int b2) {
    if (wid < 2)
      gload_lds16(sTgBase + ((size_t)gs << 4), sTl + b2 * 2048);
  };
  auto chains = [&](const char* tb, u32x4& af00, u32x4& af01,
                    u32x4& af10, u32x4& af11) {
#pragma unroll
    for (int m = 0; m < 2; ++m) {
      float tv = *(const float*)(tb + m * 256);
      float c2 = tv + tv;
      float T0 = 1.0f, T1 = tv;
      float T2  = __builtin_fmaf(c2, T1,  -T0);
      float T3  = __builtin_fmaf(c2, T2,  -T1);
      float T4  = __builtin_fmaf(c2, T3,  -T2);
      float T5  = __builtin_fmaf(c2, T4,  -T3);
      float T6  = __builtin_fmaf(c2, T5,  -T4);
      float T7  = __builtin_fmaf(c2, T6,  -T5);
      float T8  = __builtin_fmaf(c2, T7,  -T6);
      float T9  = __builtin_fmaf(c2, T8,  -T7);
      float T10 = __builtin_fmaf(c2, T9,  -T8);
      float T11 = __builtin_fmaf(c2, T10, -T9);
      float T12 = __builtin_fmaf(c2, T11, -T10);
      float T13 = __builtin_fmaf(c2, T12, -T11);
      float T14 = __builtin_fmaf(c2, T13, -T12);
      float T15 = __builtin_fmaf(c2, T14, -T13);
      u32x4 lo, hi;
      lo[0] = pk(T0,  T1);  lo[1] = pk(T2,  T3);
      lo[2] = pk(T4,  T5);  lo[3] = pk(T6,  T7);
      hi[0] = pk(T8,  T9);  hi[1] = pk(T10, T11);
      hi[2] = pk(T12, T13); hi[3] = pk(T14, T15);
      if (m == 0) { af00 = lo; af01 = hi; }
      else        { af10 = lo; af11 = hi; }
    }
  };
  auto mfma16 = [&](const char* bb, const u32x4& af00, const u32x4& af01,
                    const u32x4& af10, const u32x4& af11) {
    bf16x8 a00 = *(const bf16x8*)&af00;
    bf16x8 a01 = *(const bf16x8*)&af01;
    bf16x8 a10 = *(const bf16x8*)&af10;
    bf16x8 a11 = *(const bf16x8*)&af11;
#pragma unroll
    for (int n = 0; n < 4; ++n) {
      bf16x8 b0 = *(const bf16x8*)(bb + n * 256);
      bf16x8 b1 = *(const bf16x8*)(bb + 8192 + n * 256);
      acc[0][n] = __builtin_amdgcn_mfma_f32_16x16x32_bf16(a00, b0, acc[0][n], 0, 0, 0);
      acc[1][n] = __builtin_amdgcn_mfma_f32_16x16x32_bf16(a10, b0, acc[1][n], 0, 0, 0);
      acc[0][n] = __builtin_amdgcn_mfma_f32_16x16x32_bf16(a01, b1, acc[0][n], 0, 0, 0);
      acc[1][n] = __builtin_amdgcn_mfma_f32_16x16x32_bf16(a11, b1, acc[1][n], 0, 0, 0);
    }
  };
  auto fence = [&]() {   // counted: only the just-issued batch rides
    if (wid < 2) asm volatile("s_waitcnt vmcnt(3)" ::: "memory");
    else         asm volatile("s_waitcnt vmcnt(2)" ::: "memory");
    __builtin_amdgcn_s_barrier();
    __builtin_amdgcn_sched_barrier(0);
  };

  // prologue: stage steps 0,1 into bufs 0,1; drain batch0, leave batch1
  stageB(S0 + 0, 0); stageT(S0 + 0, 0);
  stageB(S0 + 1, 1); stageT(S0 + 1, 1);
  fence();

  auto fastbody = [&](int s, int cur) {   // cur = s&1, compile-time
    u32x4 af00, af01, af10, af11;
    chains(tb0 + cur * 2048, af00, af01, af10, af11);
    __builtin_amdgcn_s_setprio(1);
    mfma16(bb0 + cur * 16384, af00, af01, af10, af11);
    __builtin_amdgcn_s_setprio(0);
    __builtin_amdgcn_s_barrier();          // all waves done reading buf cur
    __builtin_amdgcn_sched_barrier(0);
    stageB(S0 + s + 2, cur);
    stageT(S0 + s + 2, cur);
    fence();
  };

  for (int s = 0; s < NFAST; s += 2) {
    fastbody(s, 0);
    fastbody(s + 1, 1);
  }

  if constexpr (Q < 3) {
    // tail steps 32,33: pre-staged; one full drain between
#pragma unroll
    for (int s = 32; s < 34; ++s) {
      u32x4 af00, af01, af10, af11;
      chains(tb0 + (s & 1) * 2048, af00, af01, af10, af11);
      mfma16(bb0 + (s & 1) * 16384, af00, af01, af10, af11);
      __syncthreads();
    }
  } else {
    const int row = brow + wr * 32 + l15;
    const uint16_t* x0 = xbf + (size_t)row * FD;
    const uint16_t* x1 = x0 + (size_t)16 * FD;
    // tail local steps 22..33 (basis 22..25, residual 26..33), full drains.
    for (int s = 22; s < 34; ++s) {
      u32x4 af00, af01, af10, af11;
      if (s < 26) {
        chains(tb0 + (s & 1) * 2048, af00, af01, af10, af11);
      } else {                             // residual: direct register loads
        int kres = ((s - 26) << 6) + l4 * 8;
        af00 = *(const u32x4*)(x0 + kres);
        af01 = *(const u32x4*)(x0 + kres + 32);
        af10 = *(const u32x4*)(x1 + kres);
        af11 = *(const u32x4*)(x1 + kres + 32);
      }
      mfma16(bb0 + (s & 1) * 16384, af00, af01, af10, af11);
      __syncthreads();                     // reads done + all gloads drained
      if (s + 2 <= 33) {                   // stage into the just-read buf
        stageB(S0 + s + 2, (s + 2) & 1);
        if (s + 2 <= 25) stageT(S0 + s + 2, (s + 2) & 1);
      }
    }
    __syncthreads();                       // final staging ordering (harmless)
  }

  // epilogue: bf16 partial store (C/D layout m89)
#pragma unroll
  for (int m = 0; m < 2; ++m)
#pragma unroll
    for (int n = 0; n < 4; ++n)
#pragma unroll
      for (int r = 0; r < 4; ++r) {
        int grow = brow + wr * 32 + m * 16 + l4 * 4 + r;
        int gcol = bcol + wc * 64 + n * 16 + l15;
        p[(size_t)grow * OD + gcol] = (uint16_t)bf_rtn(acc[m][n][r]);
      }
}

__global__ __launch_bounds__(512, 6) void k_gemm_q(const float* __restrict__ t,
                                                   const uint16_t* __restrict__ xbf,
                                                   const uint16_t* __restrict__ bt2,
                                                   uint16_t* __restrict__ p0,
                                                   uint16_t* __restrict__ p1,
                                                   uint16_t* __restrict__ p2,
                                                   uint16_t* __restrict__ p3) {
  __shared__ __align__(128) char lds[36864];  // B 2x16KB | t 2x2KB
  int q = blockIdx.x >> 8, bx = blockIdx.x & 255;
  if (q == 0)      gemm_q<0>(bx, lds, t, xbf, bt2, p0);
  else if (q == 1) gemm_q<1>(bx, lds, t, xbf, bt2, p1);
  else if (q == 2) gemm_q<2>(bx, lds, t, xbf, bt2, p2);
  else             gemm_q<3>(bx, lds, t, xbf, bt2, p3);
}

__global__ __launch_bounds__(256) void k_add4(float* __restrict__ out,
                                              const uint16_t* __restrict__ p0,
                                              const uint16_t* __restrict__ p1,
                                              const uint16_t* __restrict__ p2,
                                              const uint16_t* __restrict__ p3) {
  size_t i = ((size_t)blockIdx.x * 256 + threadIdx.x) * 4;
  u32x2 a0 = *(const u32x2*)(p0 + i);
  u32x2 a1 = *(const u32x2*)(p1 + i);
  u32x2 a2 = *(const u32x2*)(p2 + i);
  u32x2 a3 = *(const u32x2*)(p3 + i);
  f32x4 o;
  o[0] = (__uint_as_float(a0[0] << 16)         + __uint_as_float(a1[0] << 16)) +
         (__uint_as_float(a2[0] << 16)         + __uint_as_float(a3[0] << 16));
  o[1] = (__uint_as_float(a0[0] & 0xffff0000u) + __uint_as_float(a1[0] & 0xffff0000u)) +
         (__uint_as_float(a2[0] & 0xffff0000u) + __uint_as_float(a3[0] & 0xffff0000u));
  o[2] = (__uint_as_float(a0[1] << 16)         + __uint_as_float(a1[1] << 16)) +
         (__uint_as_float(a2[1] << 16)         + __uint_as_float(a3[1] << 16));
  o[3] = (__uint_as_float(a0[1] & 0xffff0000u) + __uint_as_float(a1[1] & 0xffff0000u)) +
         (__uint_as_float(a2[1] & 0xffff0000u) + __uint_as_float(a3[1] & 0xffff0000u));
  *(f32x4*)(out + i) = o;
}

// ============ FALLBACK (r27 verbatim): K-halves, 4-buf paired pipeline ======
template <int MODE>
__device__ __forceinline__ void gemm_h(int bx, char* lds,
                                       const float* __restrict__ t,
                                       const uint16_t* __restrict__ xbf,
                                       const uint16_t* __restrict__ bt2,
                                       uint16_t* __restrict__ p) {
  constexpr int S0 = (MODE == 2) ? 68 : 0;

  const int tid  = threadIdx.x;
  const int lane = tid & 63;
  const int wid  = tid >> 6;
  const int wr   = wid >> 1;
  const int wc   = wid & 1;
  const int l15  = lane & 15, l4 = lane >> 4;

  int idx = bx >> 3;
  int rt  = (bx & 7) * 8 + (idx >> 2);
  int ct  = idx & 3;
  const int brow = rt << 7, bcol = ct << 7;

  const char* btbase = (const char*)bt2 + (size_t)ct * BT_BYTES_PER_CT;
  const int row = brow + wr * 32 + l15;
  const uint16_t* x0 = xbf + (size_t)row * FD;
  const uint16_t* x1 = x0 + (size_t)16 * FD;

  const char* bb0 = lds + l4 * 2048 + (wc * 64 + l15) * 16;
  const char* tb0 = lds + TOFF4 + (wr * 32 + l15) * 16 + l4 * 4;
  char* sBl = lds + tid * 16;
  char* sTl = lds + TOFF4 + wid * 1024 + lane * 16;

  const char* sBgBase = btbase + (size_t)tid * 16;
  const char* sTgBase = (const char*)t + (((size_t)(brow + wid * 64 + lane)) * FD) * 4;

  f32x4 acc[2][4];
#pragma unroll
  for (int m = 0; m < 2; ++m)
#pragma unroll
    for (int n = 0; n < 4; ++n) acc[m][n] = (f32x4)0.0f;

  u32x4 pf00 = {}, pf01 = {}, pf10 = {}, pf11 = {};

  auto stageB = [&](int gs, int b2) {
    const char* src = sBgBase + ((size_t)gs << 14);
    gload_lds16(src, sBl + b2 * 16384);
    gload_lds16(src + 8192, sBl + b2 * 16384 + 8192);
  };
  auto stageT = [&](int gs, int b2) {
    if (wid < 2)
      gload_lds16(sTgBase + ((size_t)gs << 4), sTl + b2 * 2048);
  };
  auto chains = [&](const char* tb, u32x4& af00, u32x4& af01,
                    u32x4& af10, u32x4& af11) {
#pragma unroll
    for (int m = 0; m < 2; ++m) {
      float tv = *(const float*)(tb + m * 256);
      float c2 = tv + tv;
      float T0 = 1.0f, T1 = tv;
      float T2  = __builtin_fmaf(c2, T1,  -T0);
      float T3  = __builtin_fmaf(c2, T2,  -T1);
      float T4  = __builtin_fmaf(c2, T3,  -T2);
      float T5  = __builtin_fmaf(c2, T4,  -T3);
      float T6  = __builtin_fmaf(c2, T5,  -T4);
      float T7  = __builtin_fmaf(c2, T6,  -T5);
      float T8  = __builtin_fmaf(c2, T7,  -T6);
      float T9  = __builtin_fmaf(c2, T8,  -T7);
      float T10 = __builtin_fmaf(c2, T9,  -T8);
      float T11 = __builtin_fmaf(c2, T10, -T9);
      float T12 = __builtin_fmaf(c2, T11, -T10);
      float T13 = __builtin_fmaf(c2, T12, -T11);
      float T14 = __builtin_fmaf(c2, T13, -T12);
      float T15 = __builtin_fmaf(c2, T14, -T13);
      u32x4 lo, hi;
      lo[0] = pk(T0,  T1);  lo[1] = pk(T2,  T3);
      lo[2] = pk(T4,  T5);  lo[3] = pk(T6,  T7);
      hi[0] = pk(T8,  T9);  hi[1] = pk(T10, T11);
      hi[2] = pk(T12, T13); hi[3] = pk(T14, T15);
      if (m == 0) { af00 = lo; af01 = hi; }
      else        { af10 = lo; af11 = hi; }
    }
  };
  auto mfma16 = [&](const char* bb, const u32x4& af00, const u32x4& af01,
                    const u32x4& af10, const u32x4& af11) {
    bf16x8 a00 = *(const bf16x8*)&af00;
    bf16x8 a01 = *(const bf16x8*)&af01;
    bf16x8 a10 = *(const bf16x8*)&af10;
    bf16x8 a11 = *(const bf16x8*)&af11;
#pragma unroll
    for (int n = 0; n < 4; ++n) {
      bf16x8 b0 = *(const bf16x8*)(bb + n * 256);
      bf16x8 b1 = *(const bf16x8*)(bb + 8192 + n * 256);
      acc[0][n] = __builtin_amdgcn_mfma_f32_16x16x32_bf16(a00, b0, acc[0][n], 0, 0, 0);
      acc[1][n] = __builtin_amdgcn_mfma_f32_16x16x32_bf16(a10, b0, acc[1][n], 0, 0, 0);
      acc[0][n] = __builtin_amdgcn_mfma_f32_16x16x32_bf16(a01, b1, acc[0][n], 0, 0, 0);
      acc[1][n] = __builtin_amdgcn_mfma_f32_16x16x32_bf16(a11, b1, acc[1][n], 0, 0, 0);
    }
  };
  auto fence_bar = [&]() {
    if (wid < 2) asm volatile("s_waitcnt vmcnt(6)" ::: "memory");
    else         asm volatile("s_waitcnt vmcnt(4)" ::: "memory");
    __builtin_amdgcn_s_barrier();
    __builtin_amdgcn_sched_barrier(0);
  };
  auto pairbody = [&](int s, int c0, int c1) {
    u32x4 af00, af01, af10, af11;
    chains(tb0 + c0 * 2048, af00, af01, af10, af11);
    __builtin_amdgcn_s_setprio(1);
    mfma16(bb0 + c0 * 16384, af00, af01, af10, af11);
    __builtin_amdgcn_s_setprio(0);
    chains(tb0 + c1 * 2048, af00, af01, af10, af11);
    __builtin_amdgcn_s_setprio(1);
    mfma16(bb0 + c1 * 16384, af00, af01, af10, af11);
    __builtin_amdgcn_s_setprio(0);
    __builtin_amdgcn_s_barrier();
    __builtin_amdgcn_sched_barrier(0);
    stageB(S0 + s + 4, c0); stageT(S0 + s + 4, c0);
    stageB(S0 + s + 5, c1); stageT(S0 + s + 5, c1);
    fence_bar();
  };

  stageB(S0 + 0, 0); stageT(S0 + 0, 0);
  stageB(S0 + 1, 1); stageT(S0 + 1, 1);
  stageB(S0 + 2, 2); stageT(S0 + 2, 2);
  stageB(S0 + 3, 3); stageT(S0 + 3, 3);
  fence_bar();

  if constexpr (MODE == 1) {
    for (int s = 0; s < 64; s += 4) { pairbody(s, 0, 1); pairbody(s + 2, 2, 3); }
    for (int s = 64; s < 68; ++s) {
      u32x4 af00, af01, af10, af11;
      chains(tb0 + (s & 3) * 2048, af00, af01, af10, af11);
      mfma16(bb0 + (s & 3) * 16384, af00, af01, af10, af11);
      __syncthreads();
    }
  } else {
    for (int s = 0; s < 56; s += 4) { pairbody(s, 0, 1); pairbody(s + 2, 2, 3); }
    for (int s = 56; s < 68; ++s) {
      u32x4 af00 = pf00, af01 = pf01, af10 = pf10, af11 = pf11;
      if (s >= 58 && s <= 65) stageB(68 + s + 2, (s + 2) & 3);
      if (s >= 59 && s <= 66) {
        int kres = ((s + 1 - 60) << 6) + l4 * 8;
        pf00 = *(const u32x4*)(x0 + kres);
        pf01 = *(const u32x4*)(x0 + kres + 32);
        pf10 = *(const u32x4*)(x1 + kres);
        pf11 = *(const u32x4*)(x1 + kres + 32);
      }
      if (s < 60) chains(tb0 + (s & 3) * 2048, af00, af01, af10, af11);
      mfma16(bb0 + (s & 3) * 16384, af00, af01, af10, af11);
      __syncthreads();
    }
  }

#pragma unroll
  for (int m = 0; m < 2; ++m)
#pragma unroll
    for (int n = 0; n < 4; ++n)
#pragma unroll
      for (int r = 0; r < 4; ++r) {
        int grow = brow + wr * 32 + m * 16 + l4 * 4 + r;
        int gcol = bcol + wc * 64 + n * 16 + l15;
        p[(size_t)grow * OD + gcol] = (uint16_t)bf_rtn(acc[m][n][r]);
      }
}

__global__ __launch_bounds__(512, 4) void k_gemm_split(const float* __restrict__ t,
                                                       const uint16_t* __restrict__ xbf,
                                                       const uint16_t* __restrict__ bt2,
                                                       uint16_t* __restrict__ p0b,
                                                       uint16_t* __restrict__ p1b) {
  __shared__ __align__(128) char lds[73728];
  if (blockIdx.x < 256) gemm_h<1>(blockIdx.x,       lds, t, xbf, bt2, p0b);
  else                  gemm_h<2>(blockIdx.x - 256, lds, t, xbf, bt2, p1b);
}

__global__ __launch_bounds__(256) void k_add2(float* __restrict__ out,
                                              const uint16_t* __restrict__ p0b,
                                              const uint16_t* __restrict__ p1b) {
  size_t i = ((size_t)blockIdx.x * 256 + threadIdx.x) * 4;
  u32x2 q = *(const u32x2*)(p0b + i);
  u32x2 p = *(const u32x2*)(p1b + i);
  f32x4 a;
  a[0] = __uint_as_float(q[0] << 16)         + __uint_as_float(p[0] << 16);
  a[1] = __uint_as_float(q[0] & 0xffff0000u) + __uint_as_float(p[0] & 0xffff0000u);
  a[2] = __uint_as_float(q[1] << 16)         + __uint_as_float(p[1] << 16);
  a[3] = __uint_as_float(q[1] & 0xffff0000u) + __uint_as_float(p[1] & 0xffff0000u);
  *(f32x4*)(out + i) = a;
}

extern "C" void kernel_launch(void* const* d_in, const int* in_sizes, int n_in,
                              void* d_out, int out_size, void* d_ws, size_t ws_size,
                              hipStream_t stream) {
  const float* x      = (const float*)d_in[0];
  const float* coeffs = (const float*)d_in[1];
  const float* bw     = (const float*)d_in[2];
  float* out = (float*)d_out;
  char* ws = (char*)d_ws;

  float*    t   = (float*)ws;
  uint16_t* xbf = (uint16_t*)(ws + WS_T);
  uint16_t* bt2 = (uint16_t*)(ws + WS_T + WS_XBF);
  uint16_t* p0  = (uint16_t*)(ws + WS_P0_OFF);
  uint16_t* p1  = (uint16_t*)(ws + WS_P1_OFF);
  uint16_t* p2  = (uint16_t*)(ws + WS_P2_OFF);
  uint16_t* p3  = (uint16_t*)(ws + WS_P3_OFF);

  k_prep<<<5120, 256, 0, stream>>>(x, t, xbf, coeffs, bw, bt2, out);
  if (ws_size >= WS_NEED4) {
    k_gemm_q<<<1024, 512, 0, stream>>>(t, xbf, bt2, p0, p1, p2, p3);
    k_add4<<<4096, 256, 0, stream>>>(out, p0, p1, p2, p3);
  } else {
    k_gemm_split<<<512, 512, 0, stream>>>(t, xbf, bt2, p0, p1);
    k_add2<<<4096, 256, 0, stream>>>(out, p0, p1);
  }
}

// Round 30
// 101.350 us; speedup vs baseline: 1.8951x; 1.0574x over previous
//
#include <hip/hip_runtime.h>
#include <hip/hip_bf16.h>
#include <stdint.h>

#define MB_ 8192
#define FD  512
#define OD  512
#define KD  8704     // F*16 + F (basis + residual)
#define KBASIS 8192
// bt2 tiled geometry: chunk(ct, ks, o) ; ks in [0,1088), o in [0,128), 16B chunks
#define BT_KS   1088
#define BT_CHUNKS_PER_CT (BT_KS * 128)          // 139264
#define BT_BYTES_PER_CT  (BT_CHUNKS_PER_CT * 16) // 2228224
#define TOFF 65536   // t-panel LDS offset (after 4x16KB B bufs)
#define WS_T    16777216ull
#define WS_XBF  8388608ull
#define WS_BT2  8912896ull
#define WS_P0_OFF (WS_T + WS_XBF + WS_BT2)       // 34078720 (bf16 partial 0, 8MB)
#define WS_P1_OFF (WS_P0_OFF + 8388608ull)       // 42467328 (bf16 partial 1, 8MB)

typedef __attribute__((ext_vector_type(4))) float f32x4;
typedef __attribute__((ext_vector_type(8))) short bf16x8;
typedef __attribute__((ext_vector_type(4))) unsigned int u32x4;
typedef __attribute__((ext_vector_type(2))) unsigned int u32x2;

__device__ __forceinline__ void gload_lds16(const void* g, void* l) {
  __builtin_amdgcn_global_load_lds((const __attribute__((address_space(1))) void*)g,
                                   (__attribute__((address_space(3))) void*)l,
                                   16, 0, 0);
}

__device__ __forceinline__ uint32_t bf_rtn(float f) {
  uint32_t u = __float_as_uint(f);
  return (u + 0x7fffu + ((u >> 16) & 1u)) >> 16;
}

// packed bf16 pair (a in low 16, b in high 16) via HW v_cvt_pk_bf16_f32
__device__ __forceinline__ uint32_t pk(float a, float b) {
  uint32_t r;
  asm("v_cvt_pk_bf16_f32 %0, %1, %2" : "=v"(r) : "v"(a), "v"(b));
  return r;
}

// ---------------- phase 1 (fused): tanh/xbf repack + bt2 repack -------------
// blocks 0..4095: t = tanh(x) fp32, xbf = bf16(x)
// blocks 4096..5119: bt2 tiled slot-permuted repack (PROVEN r12-29)
__global__ __launch_bounds__(256) void k_prep(const float* __restrict__ x,
                                              float* __restrict__ t,
                                              uint16_t* __restrict__ xbf,
                                              const float* __restrict__ coeffs,
                                              const float* __restrict__ bw,
                                              uint16_t* __restrict__ bt2,
                                              float* __restrict__ out) {
  if (blockIdx.x < 4096) {
    int i = blockIdx.x * 256 + threadIdx.x;
    f32x4 v = ((const f32x4*)x)[i];
    f32x4 tv;
    tv[0] = tanhf(v[0]); tv[1] = tanhf(v[1]);
    tv[2] = tanhf(v[2]); tv[3] = tanhf(v[3]);
    ((f32x4*)t)[i] = tv;
    u32x2 p;
    p[0] = pk(v[0], v[1]);
    p[1] = pk(v[2], v[3]);
    ((u32x2*)xbf)[i] = p;
  } else {
    int tid = (blockIdx.x - 4096) * 256 + threadIdx.x;
    {
      int o = tid & 511, i = tid >> 9;
      const f32x4* src = (const f32x4*)(coeffs + (((size_t)(i * 512 + o)) << 4));
      f32x4 c0 = src[0], c1 = src[1], c2 = src[2], c3 = src[3];
      u32x4 qa, qb;
      qa[0] = pk(c0[0], c0[1]);
      qa[1] = pk(c0[2], c0[3]);
      qa[2] = pk(c1[0], c1[1]);
      qa[3] = pk(c1[2], c1[3]);
      qb[0] = pk(c2[0], c2[1]);
      qb[1] = pk(c2[2], c2[3]);
      qb[2] = pk(c3[0], c3[1]);
      qb[3] = pk(c3[2], c3[3]);
      int slo = ((i >> 2) << 3) | (i & 3);
      size_t cidx = (size_t)(o >> 7) * BT_CHUNKS_PER_CT + (size_t)slo * 128 + (o & 127);
      u32x4* base = (u32x4*)bt2;
      base[cidx]       = qa;
      base[cidx + 512] = qb;
    }
    {
      int o2 = tid >> 9, i2 = tid & 511;
      size_t cidx = (size_t)(o2 >> 7) * BT_CHUNKS_PER_CT + (size_t)(1024 + (i2 >> 3)) * 128 + (o2 & 127);
      bt2[cidx * 8 + (i2 & 7)] = (uint16_t)bf_rtn(bw[i2 * 512 + o2]);
    }
    if (tid == 0) out[(size_t)MB_ * OD] = 0.0f;
  }
}

// ---------------- phase 2: fused GEMM body, 4-buf counted pipeline ----------
// MODE 1: K-half 0 (steps 0..67, all basis) -> bf16 partial (p0b).
// MODE 2: K-half 1 (68..135, incl residual) -> bf16 partial (p1b).
// 4 LDS bufs (72KB -> 2 blocks/CU at grid 512): stage-AFTER-compute into the
// just-consumed bufs, guarded by mid-pair s_barrier + counted fence vmcnt(6/4).
// PROVEN r27 (best measured: total 101.7us; gemm 82.4us at DS-pipe plateau).
template <int MODE>
__device__ __forceinline__ void gemm_body(int bx, char* lds,
                                          const float* __restrict__ t,
                                          const uint16_t* __restrict__ xbf,
                                          const uint16_t* __restrict__ bt2,
                                          uint16_t* __restrict__ p) {
  constexpr int S0 = (MODE == 2) ? 68 : 0;

  const int tid  = threadIdx.x;       // 0..511
  const int lane = tid & 63;
  const int wid  = tid >> 6;          // 0..7
  const int wr   = wid >> 1;          // 0..3 (row group of 32)
  const int wc   = wid & 1;           // 0..1 (col group of 64)
  const int l15  = lane & 15, l4 = lane >> 4;

  // bijective XCD swizzle over the 256 tiles
  int idx = bx >> 3;
  int rt  = (bx & 7) * 8 + (idx >> 2);   // 0..63
  int ct  = idx & 3;                     // 0..3
  const int brow = rt << 7, bcol = ct << 7;

  const char* btbase = (const char*)bt2 + (size_t)ct * BT_BYTES_PER_CT;
  const int row = brow + wr * 32 + l15;
  const uint16_t* x0 = xbf + (size_t)row * FD;
  const uint16_t* x1 = x0 + (size_t)16 * FD;

  const char* bb0 = lds + l4 * 2048 + (wc * 64 + l15) * 16;       // B reads
  const char* tb0 = lds + TOFF + (wr * 32 + l15) * 16 + l4 * 4;   // t reads
  char* sBl = lds + tid * 16;                                     // B stage dst
  char* sTl = lds + TOFF + wid * 1024 + lane * 16;                // t stage dst

  const char* sBgBase = btbase + (size_t)tid * 16;
  const char* sTgBase = (const char*)t + (((size_t)(brow + wid * 64 + lane)) * FD) * 4;

  f32x4 acc[2][4];
#pragma unroll
  for (int m = 0; m < 2; ++m)
#pragma unroll
    for (int n = 0; n < 4; ++n) acc[m][n] = (f32x4)0.0f;

  u32x4 pf00 = {}, pf01 = {}, pf10 = {}, pf11 = {};   // residual prefetch

  auto stageB = [&](int gs, int b2) {       // 2 loads/thread (16KB panel)
    const char* src = sBgBase + ((size_t)gs << 14);
    gload_lds16(src, sBl + b2 * 16384);
    gload_lds16(src + 8192, sBl + b2 * 16384 + 8192);
  };
  auto stageT = [&](int gs, int b2) {       // stage t for basis step gs
    if (wid < 2)
      gload_lds16(sTgBase + ((size_t)gs << 4), sTl + b2 * 2048);
  };
  auto chains = [&](const char* tb, u32x4& af00, u32x4& af01,
                    u32x4& af10, u32x4& af11) {
#pragma unroll
    for (int m = 0; m < 2; ++m) {
      float tv = *(const float*)(tb + m * 256);
      float c2 = tv + tv;
      float T0 = 1.0f, T1 = tv;
      float T2  = __builtin_fmaf(c2, T1,  -T0);
      float T3  = __builtin_fmaf(c2, T2,  -T1);
      float T4  = __builtin_fmaf(c2, T3,  -T2);
      float T5  = __builtin_fmaf(c2, T4,  -T3);
      float T6  = __builtin_fmaf(c2, T5,  -T4);
      float T7  = __builtin_fmaf(c2, T6,  -T5);
      float T8  = __builtin_fmaf(c2, T7,  -T6);
      float T9  = __builtin_fmaf(c2, T8,  -T7);
      float T10 = __builtin_fmaf(c2, T9,  -T8);
      float T11 = __builtin_fmaf(c2, T10, -T9);
      float T12 = __builtin_fmaf(c2, T11, -T10);
      float T13 = __builtin_fmaf(c2, T12, -T11);
      float T14 = __builtin_fmaf(c2, T13, -T12);
      float T15 = __builtin_fmaf(c2, T14, -T13);
      u32x4 lo, hi;
      lo[0] = pk(T0,  T1);  lo[1] = pk(T2,  T3);
      lo[2] = pk(T4,  T5);  lo[3] = pk(T6,  T7);
      hi[0] = pk(T8,  T9);  hi[1] = pk(T10, T11);
      hi[2] = pk(T12, T13); hi[3] = pk(T14, T15);
      if (m == 0) { af00 = lo; af01 = hi; }
      else        { af10 = lo; af11 = hi; }
    }
  };
  auto mfma16 = [&](const char* bb, const u32x4& af00, const u32x4& af01,
                    const u32x4& af10, const u32x4& af11) {
    bf16x8 a00 = *(const bf16x8*)&af00;
    bf16x8 a01 = *(const bf16x8*)&af01;
    bf16x8 a10 = *(const bf16x8*)&af10;
    bf16x8 a11 = *(const bf16x8*)&af11;
#pragma unroll
    for (int n = 0; n < 4; ++n) {
      bf16x8 b0 = *(const bf16x8*)(bb + n * 256);          // h=0
      bf16x8 b1 = *(const bf16x8*)(bb + 8192 + n * 256);   // h=1
      acc[0][n] = __builtin_amdgcn_mfma_f32_16x16x32_bf16(a00, b0, acc[0][n], 0, 0, 0);
      acc[1][n] = __builtin_amdgcn_mfma_f32_16x16x32_bf16(a10, b0, acc[1][n], 0, 0, 0);
      acc[0][n] = __builtin_amdgcn_mfma_f32_16x16x32_bf16(a01, b1, acc[0][n], 0, 0, 0);
      acc[1][n] = __builtin_amdgcn_mfma_f32_16x16x32_bf16(a11, b1, acc[1][n], 0, 0, 0);
    }
  };
  auto fence_bar = [&]() {   // counted: only the just-issued pair rides
    if (wid < 2) asm volatile("s_waitcnt vmcnt(6)" ::: "memory");
    else         asm volatile("s_waitcnt vmcnt(4)" ::: "memory");
    __builtin_amdgcn_s_barrier();
    __builtin_amdgcn_sched_barrier(0);
  };
  auto pairbody = [&](int s, int c0, int c1) {
    u32x4 af00, af01, af10, af11;
    chains(tb0 + c0 * 2048, af00, af01, af10, af11);
    __builtin_amdgcn_s_setprio(1);
    mfma16(bb0 + c0 * 16384, af00, af01, af10, af11);
    __builtin_amdgcn_s_setprio(0);
    chains(tb0 + c1 * 2048, af00, af01, af10, af11);
    __builtin_amdgcn_s_setprio(1);
    mfma16(bb0 + c1 * 16384, af00, af01, af10, af11);
    __builtin_amdgcn_s_setprio(0);
    __builtin_amdgcn_s_barrier();            // all waves done reading c0,c1
    __builtin_amdgcn_sched_barrier(0);       // pin: no hoist of the overwrite
    stageB(S0 + s + 4, c0); stageT(S0 + s + 4, c0);
    stageB(S0 + s + 5, c1); stageT(S0 + s + 5, c1);
    fence_bar();
  };

  // prologue: stage steps 0..3 into bufs 0..3; drain pair(0,1), leave (2,3)
  stageB(S0 + 0, 0); stageT(S0 + 0, 0);
  stageB(S0 + 1, 1); stageT(S0 + 1, 1);
  stageB(S0 + 2, 2); stageT(S0 + 2, 2);
  stageB(S0 + 3, 3); stageT(S0 + 3, 3);
  fence_bar();

  if constexpr (MODE == 1) {                         // steps 0..67, all basis
    for (int s = 0; s < 64; s += 4) { pairbody(s, 0, 1); pairbody(s + 2, 2, 3); }
    for (int s = 64; s < 68; ++s) {                  // tail: pre-staged
      u32x4 af00, af01, af10, af11;
      chains(tb0 + (s & 3) * 2048, af00, af01, af10, af11);
      mfma16(bb0 + (s & 3) * 16384, af00, af01, af10, af11);
      __syncthreads();
    }
  } else {                                           // steps 68..135 (local 0..67)
    for (int s = 0; s < 56; s += 4) { pairbody(s, 0, 1); pairbody(s + 2, 2, 3); }
    for (int s = 56; s < 68; ++s) {                  // tail (global 124..135)
      u32x4 af00 = pf00, af01 = pf01, af10 = pf10, af11 = pf11;
      if (s >= 58 && s <= 65) stageB(68 + s + 2, (s + 2) & 3);   // residual B
      if (s >= 59 && s <= 66) {
        int kres = ((s + 1 - 60) << 6) + l4 * 8;
        pf00 = *(const u32x4*)(x0 + kres);
        pf01 = *(const u32x4*)(x0 + kres + 32);
        pf10 = *(const u32x4*)(x1 + kres);
        pf11 = *(const u32x4*)(x1 + kres + 32);
      }
      if (s < 60) chains(tb0 + (s & 3) * 2048, af00, af01, af10, af11);
      mfma16(bb0 + (s & 3) * 16384, af00, af01, af10, af11);
      __syncthreads();
    }
  }

  // epilogue: bf16 partial store (C/D layout m89)
#pragma unroll
  for (int m = 0; m < 2; ++m)
#pragma unroll
    for (int n = 0; n < 4; ++n)
#pragma unroll
      for (int r = 0; r < 4; ++r) {
        int grow = brow + wr * 32 + m * 16 + l4 * 4 + r;
        int gcol = bcol + wc * 64 + n * 16 + l15;
        p[(size_t)grow * OD + gcol] = (uint16_t)bf_rtn(acc[m][n][r]);
      }
}

__global__ __launch_bounds__(512, 4) void k_gemm_split(const float* __restrict__ t,
                                                       const uint16_t* __restrict__ xbf,
                                                       const uint16_t* __restrict__ bt2,
                                                       uint16_t* __restrict__ p0b,
                                                       uint16_t* __restrict__ p1b) {
  __shared__ __align__(128) char lds[73728];  // B 4x16KB | t 4x2KB
  if (blockIdx.x < 256) gemm_body<1>(blockIdx.x,       lds, t, xbf, bt2, p0b);
  else                  gemm_body<2>(blockIdx.x - 256, lds, t, xbf, bt2, p1b);
}

// ---------------- phase 3: out = bf16(p0) + bf16(p1) ------------------------
__global__ __launch_bounds__(256) void k_add(float* __restrict__ out,
                                             const uint16_t* __restrict__ p0b,
                                             const uint16_t* __restrict__ p1b) {
  size_t i = ((size_t)blockIdx.x * 256 + threadIdx.x) * 4;   // 4 elems/thread
  u32x2 q = *(const u32x2*)(p0b + i);
  u32x2 p = *(const u32x2*)(p1b + i);
  f32x4 a;
  a[0] = __uint_as_float(q[0] << 16)         + __uint_as_float(p[0] << 16);
  a[1] = __uint_as_float(q[0] & 0xffff0000u) + __uint_as_float(p[0] & 0xffff0000u);
  a[2] = __uint_as_float(q[1] << 16)         + __uint_as_float(p[1] << 16);
  a[3] = __uint_as_float(q[1] & 0xffff0000u) + __uint_as_float(p[1] & 0xffff0000u);
  *(f32x4*)(out + i) = a;
}

extern "C" void kernel_launch(void* const* d_in, const int* in_sizes, int n_in,
                              void* d_out, int out_size, void* d_ws, size_t ws_size,
                              hipStream_t stream) {
  const float* x      = (const float*)d_in[0];
  const float* coeffs = (const float*)d_in[1];
  const float* bw     = (const float*)d_in[2];
  float* out = (float*)d_out;
  char* ws = (char*)d_ws;

  float*    t   = (float*)ws;                          // 16 MB fp32 tanh
  uint16_t* xbf = (uint16_t*)(ws + WS_T);              // 8 MB bf16 x
  uint16_t* bt2 = (uint16_t*)(ws + WS_T + WS_XBF);     // 8.5 MB tiled B
  uint16_t* p0b = (uint16_t*)(ws + WS_P0_OFF);         // 8 MB bf16 partial 0
  uint16_t* p1b = (uint16_t*)(ws + WS_P1_OFF);         // 8 MB bf16 partial 1

  k_prep<<<5120, 256, 0, stream>>>(x, t, xbf, coeffs, bw, bt2, out);
  k_gemm_split<<<512, 512, 0, stream>>>(t, xbf, bt2, p0b, p1b);
  k_add<<<4096, 256, 0, stream>>>(out, p0b, p1b);
}